// Round 6
// baseline (99.011 us; speedup 1.0000x reference)
//
#include <hip/hip_runtime.h>

// FeatureAttention == self-attention: out[b,j,:] = gamma * softmax_i(s * <x_j,x_i>) @ x,
// s = dot(w_f, w_g).  B=4, N=4096, D=64, fp32 in/out.
//
// Round 6: occupancy attack. LDS = 40960 B exactly (KH 16K + VT 16K + PB 8K)
// -> 4 blocks/CU (160KB/40960), 16 waves/CU. PB shrunk to per-kc 32-key chunks
// (LDP=32, XOR swizzle on 8B units by row&3 -> 2-way conflicts = free).
// Staging via global_load_lds w=16 (low VGPR; cross-block TLP covers the drain).
// KS=4 -> grid 1024 = exactly 4 blocks/CU, 8 iterations, clean 16-tile splits.
// Rest as round 3b: fp16 inner dtype, S^T = K*Q^T, fixed softmax max, partial
// (O,l) to ws, merge normalizes. Fallback: round-1 bf16 kernel if ws too small.

#define N_SEQ 4096
#define KS    4
#define LOG2E 1.4426950408889634f

typedef __attribute__((ext_vector_type(8))) short short8;
typedef __attribute__((ext_vector_type(4))) short short4v;
typedef __attribute__((ext_vector_type(4))) float f4;
typedef _Float16 half8  __attribute__((ext_vector_type(8)));
typedef _Float16 half4v __attribute__((ext_vector_type(4)));
typedef _Float16 half2t __attribute__((ext_vector_type(2)));
typedef __fp16   fp16x2 __attribute__((ext_vector_type(2)));

union U8  { short8 v8; short4v v4[2]; unsigned short u[8]; };
union HU8 { half8 v; half2t h2[4]; unsigned short u[8]; };
union HU4 { half4v v; half2t h2[2]; unsigned short u[4]; };
union PK  { fp16x2 f; half2t h; };

#define MFMA16(a,b,c) __builtin_amdgcn_mfma_f32_16x16x32_bf16(a,b,c,0,0,0)
#define MFMAH(a,b,c)  __builtin_amdgcn_mfma_f32_16x16x32_f16(a,b,c,0,0,0)

static __device__ __forceinline__ unsigned short f2bf(float f){
  unsigned int u = __float_as_uint(f);
  u += 0x7fffu + ((u>>16)&1u);          // RNE
  return (unsigned short)(u>>16);
}
static __device__ __forceinline__ float bf2f(unsigned short b){
  return __uint_as_float(((unsigned int)b)<<16);
}
static __device__ __forceinline__ half2t pkrtz(float a, float b){
#if __has_builtin(__builtin_amdgcn_cvt_pkrtz)
  PK u; u.f = __builtin_amdgcn_cvt_pkrtz(a, b);
  return u.h;
#else
  half2t r; r.x = (_Float16)a; r.y = (_Float16)b; return r;
#endif
}
static __device__ __forceinline__ float fexp2(float x){
#if __has_builtin(__builtin_amdgcn_exp2f)
  return __builtin_amdgcn_exp2f(x);
#else
  return exp2f(x);
#endif
}
static __device__ __forceinline__ f4 splat4(float v){ f4 r; r.x=v; r.y=v; r.z=v; r.w=v; return r; }
static __device__ __forceinline__ f4 exp2v(f4 v){
  f4 r; r.x=fexp2(v.x); r.y=fexp2(v.y); r.z=fexp2(v.z); r.w=fexp2(v.w); return r;
}
static __device__ __forceinline__ f4 max4(f4 a, f4 b){
  f4 r; r.x=fmaxf(a.x,b.x); r.y=fmaxf(a.y,b.y); r.z=fmaxf(a.z,b.z); r.w=fmaxf(a.w,b.w); return r;
}
static __device__ __forceinline__ f4 shx4(f4 v, int m){
  f4 r; r.x=__shfl_xor(v.x,m,64); r.y=__shfl_xor(v.y,m,64);
        r.z=__shfl_xor(v.z,m,64); r.w=__shfl_xor(v.w,m,64); return r;
}
static __device__ __forceinline__ void gld_lds16(const void* g, void* l){
  __builtin_amdgcn_global_load_lds(
      (const __attribute__((address_space(1))) unsigned int*)g,
      (__attribute__((address_space(3))) unsigned int*)l, 16, 0, 0);
}

// ---------------- prep: x(fp32) -> XH [B][N][64] fp16, XT [B][64][N] fp16 ----------
__global__ __launch_bounds__(256) void prep_kernel(
    const float* __restrict__ x, unsigned short* __restrict__ xh,
    unsigned short* __restrict__ xt)
{
  __shared__ unsigned short T[64][66];
  const int tid = threadIdx.x;
  const int bb  = blockIdx.x >> 6;
  const int n0  = (blockIdx.x & 63) << 6;
  {
    const int r  = tid >> 2;
    const int c4 = tid & 3;
    const float* src = x + ((size_t)(bb*N_SEQ + n0 + r))*64 + c4*16;
    unsigned short h[16];
    #pragma unroll
    for (int i = 0; i < 4; ++i) {
      const float4 f = *(const float4*)(src + i*4);
      HU4 u; u.h2[0] = pkrtz(f.x, f.y); u.h2[1] = pkrtz(f.z, f.w);
      h[i*4+0]=u.u[0]; h[i*4+1]=u.u[1]; h[i*4+2]=u.u[2]; h[i*4+3]=u.u[3];
    }
    unsigned short* dst = xh + ((size_t)(bb*N_SEQ + n0 + r))*64 + c4*16;
    U8 u0, u1;
    #pragma unroll
    for (int j = 0; j < 8; ++j) { u0.u[j]=h[j]; u1.u[j]=h[8+j]; }
    *(short8*)dst = u0.v8; *(short8*)(dst+8) = u1.v8;
    #pragma unroll
    for (int j = 0; j < 16; ++j) T[r][c4*16+j] = h[j];
  }
  __syncthreads();
  {
    const int d = tid >> 2;
    const int g = tid & 3;
    unsigned short o[16];
    #pragma unroll
    for (int j = 0; j < 16; ++j) o[j] = T[g*16+j][d];
    unsigned short* dst = xt + ((size_t)(bb*64 + d))*N_SEQ + n0 + g*16;
    U8 u0, u1;
    #pragma unroll
    for (int j = 0; j < 8; ++j) { u0.u[j]=o[j]; u1.u[j]=o[8+j]; }
    *(short8*)dst = u0.v8; *(short8*)(dst+8) = u1.v8;
  }
}

// ---------------- attention (key-split partial, fp16, 4 blocks/CU) ----------------
__global__ __launch_bounds__(256, 4) void fattn4_kernel(
    const float* __restrict__ x, const float* __restrict__ wf,
    const float* __restrict__ wg,
    const unsigned short* __restrict__ xh, const unsigned short* __restrict__ xt,
    float* __restrict__ OP, float* __restrict__ LP)
{
  __shared__ __align__(16) unsigned short KH[2][4096];  // [hh][64k x 64d], ld=64, swizzled
  __shared__ __align__(16) unsigned short VT[2][4096];  // [hh][64d x 64k], ld=64, swizzled
  __shared__ __align__(16) unsigned short PB[4][1024];  // per-wave P chunk [32 q][32 key]

  const int tid  = threadIdx.x;
  const int lane = tid & 63;
  const int wv   = tid >> 6;
  const int mg   = wv & 1;
  const int hh   = wv >> 1;
  const int quad = lane >> 4;
  const int l15  = lane & 15;
  const int swz  = l15 & 7;
  const int psw  = (l15 & 3) << 1;   // PB 8B-unit XOR swizzle (row-determined)
  const int ks   = blockIdx.x >> 8;
  const int rem  = blockIdx.x & 255;
  const int bb   = rem >> 6;
  const int qb   = (rem & 63) << 6;

  float s = 0.f;
  #pragma unroll
  for (int i = 0; i < 32; ++i) s += wf[i]*wg[i];
  const float s2 = s * LOG2E;

  const float* xb = x + ((size_t)bb * N_SEQ) * 64;

  // Q fragments (B-operand layout: [n=l15][k=quad*8+j]), scaled by s2, fp16
  half8 qf[2][2];
  #pragma unroll
  for (int mt = 0; mt < 2; ++mt) {
    const int row = qb + mg*32 + mt*16 + l15;
    #pragma unroll
    for (int c = 0; c < 2; ++c) {
      const float* src = xb + row*64 + c*32 + quad*8;
      const float4 a0 = *(const float4*)src;
      const float4 a1 = *(const float4*)(src+4);
      HU8 u;
      u.h2[0] = pkrtz(a0.x*s2, a0.y*s2);
      u.h2[1] = pkrtz(a0.z*s2, a0.w*s2);
      u.h2[2] = pkrtz(a1.x*s2, a1.y*s2);
      u.h2[3] = pkrtz(a1.z*s2, a1.w*s2);
      qf[mt][c] = u.v;
    }
  }

  f4 Oc[2][4];
  f4 lsa[2];
  #pragma unroll
  for (int mt = 0; mt < 2; ++mt) {
    lsa[mt] = splat4(0.f);
    #pragma unroll
    for (int nt = 0; nt < 4; ++nt) Oc[mt][nt] = splat4(0.f);
  }

  const int kbb = ks*1024;   // block key base; wave key range kbb + hh*512 + t*64
  unsigned short* PBw = PB[wv];

  #pragma unroll 1
  for (int t = 0; t < 8; ++t) {
    // ---- stage both hh tiles via global_load_lds (XOR-swizzled) ----
    const int kt = kbb + t*64;
    #pragma unroll
    for (int i = 0; i < 8; ++i) {
      const int reg = i >> 1;             // 0,1: KH h; 2,3: VT h
      const int h   = reg & 1;
      const int ch  = wv*2 + (i & 1);     // chunk 0..7 (1KB each)
      const int p   = ch*64 + lane;       // 16B-unit position in 8KB tile
      const int rr  = p >> 3;
      const int cg  = (p & 7) ^ (rr & 7);
      if (reg < 2) {
        gld_lds16(xh + ((size_t)(bb*N_SEQ + kt + h*512 + rr))*64 + cg*8, &KH[h][ch*512]);
      } else {
        gld_lds16(xt + ((size_t)(bb*64 + rr))*N_SEQ + (kt + h*512 + cg*8), &VT[h][ch*512]);
      }
    }
    __syncthreads();

    // ---- S^T = K * Q^T : C rows = keys (quad*4+reg), cols = q (l15) ----
    f4 St[4][2];
    #pragma unroll
    for (int k2 = 0; k2 < 4; ++k2)
      #pragma unroll
      for (int mt = 0; mt < 2; ++mt) St[k2][mt] = splat4(0.f);

    #pragma unroll
    for (int c = 0; c < 2; ++c) {
      half8 kf[4];
      #pragma unroll
      for (int k2 = 0; k2 < 4; ++k2)
        kf[k2] = *(const half8*)&KH[hh][(k2*16 + l15)*64 + (((c*4 + quad) ^ swz))*8];
      #pragma unroll
      for (int k2 = 0; k2 < 4; ++k2)
        #pragma unroll
        for (int mt = 0; mt < 2; ++mt)
          St[k2][mt] = MFMAH(kf[k2], qf[mt][c], St[k2][mt]);
    }

    // ---- per-kc: p = exp2(S), pack into PB chunk (32 keys), read A-frag, PV ----
    #pragma unroll
    for (int kc = 0; kc < 2; ++kc) {
      #pragma unroll
      for (int k2l = 0; k2l < 2; ++k2l) {
        const int k2 = kc*2 + k2l;
        #pragma unroll
        for (int mt = 0; mt < 2; ++mt) {
          const f4 p = exp2v(St[k2][mt]);
          lsa[mt] += p;
          HU4 u; u.h2[0] = pkrtz(p.x, p.y); u.h2[1] = pkrtz(p.z, p.w);
          const int unit = (k2l*4 + quad) ^ psw;     // 8B unit within 32-key row
          *(half4v*)&PBw[(mt*16 + l15)*32 + unit*4] = u.v;
        }
      }
      half8 pa[2];
      #pragma unroll
      for (int mt = 0; mt < 2; ++mt) {
        const int u0 = (2*quad) ^ psw;               // 16B-aligned pair of units
        pa[mt] = *(const half8*)&PBw[(mt*16 + l15)*32 + u0*4];
      }
      #pragma unroll
      for (int nt = 0; nt < 4; ++nt) {
        const half8 vb = *(const half8*)&VT[hh][(nt*16 + l15)*64 + (((kc*4 + quad) ^ swz))*8];
        #pragma unroll
        for (int mt = 0; mt < 2; ++mt)
          Oc[mt][nt] = MFMAH(pa[mt], vb, Oc[mt][nt]);
      }
    }
    __syncthreads();   // tile consumed; safe to restage next iter
  }

  // ---- finalize l (sum over quads; q = mt*16+l15) ----
  float lsum[2];
  #pragma unroll
  for (int mt = 0; mt < 2; ++mt) {
    float sv = lsa[mt].x + lsa[mt].y + lsa[mt].z + lsa[mt].w;
    sv += __shfl_xor(sv, 16, 64);
    sv += __shfl_xor(sv, 32, 64);
    lsum[mt] = sv;
  }

  // ---- in-block merge of the two key halves (pure sums), write partial ----
  float* MO = (float*)KH;   // 64x64 fp32 = 16 KB
  float* ML = (float*)VT;   // l[64]
  if (hh == 1) {
    #pragma unroll
    for (int mt = 0; mt < 2; ++mt) {
      const int rbase = mg*32 + mt*16 + quad*4;
      #pragma unroll
      for (int nt = 0; nt < 4; ++nt) {
        MO[(rbase+0)*64 + nt*16 + l15] = Oc[mt][nt].x;
        MO[(rbase+1)*64 + nt*16 + l15] = Oc[mt][nt].y;
        MO[(rbase+2)*64 + nt*16 + l15] = Oc[mt][nt].z;
        MO[(rbase+3)*64 + nt*16 + l15] = Oc[mt][nt].w;
      }
      if (quad == 0) ML[mg*32 + mt*16 + l15] = lsum[mt];
    }
  }
  __syncthreads();
  if (hh == 0) {
    float* op = OP + (size_t)blockIdx.x * 4096;
    #pragma unroll
    for (int mt = 0; mt < 2; ++mt) {
      const int rbase = mg*32 + mt*16 + quad*4;
      #pragma unroll
      for (int nt = 0; nt < 4; ++nt) {
        #pragma unroll
        for (int rg = 0; rg < 4; ++rg) {
          const int rr = rbase + rg;
          op[rr*64 + nt*16 + l15] = Oc[mt][nt][rg] + MO[rr*64 + nt*16 + l15];
        }
      }
      if (quad == 0)
        LP[(size_t)blockIdx.x*64 + mg*32 + mt*16 + l15] = lsum[mt] + ML[mg*32 + mt*16 + l15];
    }
  }
}

// ---------------- merge: out = gamma * sum_s O_s / sum_s l_s ----------------
__global__ __launch_bounds__(256) void merge_kernel(
    const float* __restrict__ OP, const float* __restrict__ LP,
    const float* __restrict__ gm, float* __restrict__ out)
{
  const int idx = blockIdx.x*256 + threadIdx.x;
  const int e0  = idx*4;
  const int d0  = e0 & 63;
  const int row = e0 >> 6;
  const int bb  = row >> 12;
  const int q   = row & 4095;
  const int qt  = q >> 6;
  const int qr  = q & 63;
  float4 acc = make_float4(0.f,0.f,0.f,0.f);
  float l = 0.f;
  #pragma unroll
  for (int sct = 0; sct < KS; ++sct) {
    const int blk = sct*256 + bb*64 + qt;
    const float4 o = *(const float4*)(OP + (size_t)blk*4096 + qr*64 + d0);
    acc.x += o.x; acc.y += o.y; acc.z += o.z; acc.w += o.w;
    l += LP[(size_t)blk*64 + qr];
  }
  const float w = gm[0] / l;
  float4 r; r.x = acc.x*w; r.y = acc.y*w; r.z = acc.z*w; r.w = acc.w*w;
  *(float4*)(out + e0) = r;
}

// ---------------- fallback (round-1 kernel, no workspace) ----------------
#define LDKF 72
#define TILEF (64*LDKF)
#define LDP 36

__global__ __launch_bounds__(256) void fattn_fallback(
    const float* __restrict__ x, const float* __restrict__ wf,
    const float* __restrict__ wg, const float* __restrict__ gm,
    float* __restrict__ out)
{
  __shared__ __align__(16) unsigned short KHI[2*TILEF];
  __shared__ __align__(16) unsigned short KLO[2*TILEF];
  __shared__ __align__(16) unsigned short VT [2*TILEF];
  __shared__ __align__(16) unsigned short PB [4*32*LDP];

  const int tid  = threadIdx.x;
  const int lane = tid & 63;
  const int wv   = tid >> 6;
  const int mg   = wv & 1;
  const int hh   = wv >> 1;
  const int quad = lane >> 4;
  const int l15  = lane & 15;
  const int bb   = blockIdx.x >> 6;
  const int qb   = (blockIdx.x & 63) << 6;

  float s = 0.f;
  #pragma unroll
  for (int i = 0; i < 32; ++i) s += wf[i]*wg[i];
  const float s2 = s * LOG2E;
  const float gamma = gm[0];

  const float* xb = x + ((size_t)bb * N_SEQ) * 64;

  short8 qhf[2][2], qlf[2][2];
  #pragma unroll
  for (int mt = 0; mt < 2; ++mt) {
    const int row = qb + mg*32 + mt*16 + l15;
    #pragma unroll
    for (int c = 0; c < 2; ++c) {
      const float* src = xb + row*64 + c*32 + quad*8;
      const float4 a0 = *(const float4*)src;
      const float4 a1 = *(const float4*)(src+4);
      float qv[8] = {a0.x,a0.y,a0.z,a0.w,a1.x,a1.y,a1.z,a1.w};
      U8 vh, vl;
      #pragma unroll
      for (int j = 0; j < 8; ++j) {
        float q = qv[j]*s2;
        unsigned short hb = f2bf(q);
        vh.u[j] = (short)hb;
        vl.u[j] = (short)f2bf(q - bf2f(hb));
      }
      qhf[mt][c] = vh.v8; qlf[mt][c] = vl.v8;
    }
  }

  f4 Oc[2][4], mo[2], ls[2];
  #pragma unroll
  for (int mt = 0; mt < 2; ++mt) {
    mo[mt] = splat4(-1e30f);
    ls[mt] = splat4(0.f);
    #pragma unroll
    for (int nt = 0; nt < 4; ++nt) Oc[mt][nt] = splat4(0.f);
  }

  const int sh   = tid >> 7;
  const int srow = (tid & 127) >> 1;
  const int sch  = tid & 1;

  float4 sr[8];
  {
    const float* sp = xb + (sh*2048 + srow)*64 + sch*32;
    #pragma unroll
    for (int i = 0; i < 8; ++i) sr[i] = *(const float4*)(sp + i*4);
    unsigned short hb[32], lb[32];
    #pragma unroll
    for (int i = 0; i < 8; ++i) {
      float vv[4] = {sr[i].x, sr[i].y, sr[i].z, sr[i].w};
      #pragma unroll
      for (int j = 0; j < 4; ++j) {
        unsigned short h = f2bf(vv[j]);
        hb[i*4+j] = h;
        lb[i*4+j] = f2bf(vv[j] - bf2f(h));
      }
    }
    const int kbase = sh*TILEF + srow*LDKF + sch*32;
    #pragma unroll
    for (int g = 0; g < 4; ++g) {
      U8 wh, wl;
      #pragma unroll
      for (int j = 0; j < 8; ++j) { wh.u[j]=(short)hb[g*8+j]; wl.u[j]=(short)lb[g*8+j]; }
      *(short8*)&KHI[kbase+g*8] = wh.v8;
      *(short8*)&KLO[kbase+g*8] = wl.v8;
    }
    #pragma unroll
    for (int j = 0; j < 32; ++j) VT[sh*TILEF + (sch*32+j)*LDKF + srow] = hb[j];
  }
  __syncthreads();

  #pragma unroll 1
  for (int t = 0; t < 32; ++t) {
    if (t+1 < 32) {
      const float* sp = xb + (sh*2048 + (t+1)*64 + srow)*64 + sch*32;
      #pragma unroll
      for (int i = 0; i < 8; ++i) sr[i] = *(const float4*)(sp + i*4);
    }

    f4 Sa[2][4];
    #pragma unroll
    for (int mt = 0; mt < 2; ++mt)
      #pragma unroll
      for (int n = 0; n < 4; ++n) Sa[mt][n] = splat4(0.f);

    const int kldsb = hh*TILEF;
    #pragma unroll
    for (int n = 0; n < 4; ++n) {
      #pragma unroll
      for (int c = 0; c < 2; ++c) {
        const int off = kldsb + (n*16 + l15)*LDKF + c*32 + quad*8;
        const short8 bh = *(const short8*)&KHI[off];
        const short8 bl = *(const short8*)&KLO[off];
        #pragma unroll
        for (int mt = 0; mt < 2; ++mt) {
          Sa[mt][n] = MFMA16(qhf[mt][c], bh, Sa[mt][n]);
          Sa[mt][n] = MFMA16(qlf[mt][c], bh, Sa[mt][n]);
          Sa[mt][n] = MFMA16(qhf[mt][c], bl, Sa[mt][n]);
        }
      }
    }

    f4 p[2][4];
    #pragma unroll
    for (int mt = 0; mt < 2; ++mt) {
      f4 rm = max4(max4(Sa[mt][0],Sa[mt][1]), max4(Sa[mt][2],Sa[mt][3]));
      rm = max4(rm, shx4(rm,1));
      rm = max4(rm, shx4(rm,2));
      rm = max4(rm, shx4(rm,4));
      rm = max4(rm, shx4(rm,8));
      f4 mn = max4(mo[mt], rm);
      f4 al = exp2v(mo[mt] - mn);
      mo[mt] = mn;
      f4 rs = splat4(0.f);
      #pragma unroll
      for (int n = 0; n < 4; ++n) { p[mt][n] = exp2v(Sa[mt][n] - mn); rs += p[mt][n]; }
      rs += shx4(rs,1); rs += shx4(rs,2); rs += shx4(rs,4); rs += shx4(rs,8);
      ls[mt] = ls[mt]*al + rs;
      #pragma unroll
      for (int nt = 0; nt < 4; ++nt) Oc[mt][nt] *= al;
    }

    const int pw = wv * (32*LDP);
    #pragma unroll
    for (int kc = 0; kc < 2; ++kc) {
      #pragma unroll
      for (int mt = 0; mt < 2; ++mt) {
        #pragma unroll
        for (int n2 = 0; n2 < 2; ++n2) {
          const f4 pv = p[mt][kc*2+n2];
          const int base = pw + (mt*16 + quad*4)*LDP + n2*16 + l15;
          ((unsigned short*)PB)[base        ] = f2bf(pv.x);
          ((unsigned short*)PB)[base +   LDP] = f2bf(pv.y);
          ((unsigned short*)PB)[base + 2*LDP] = f2bf(pv.z);
          ((unsigned short*)PB)[base + 3*LDP] = f2bf(pv.w);
        }
      }
      short8 pa[2];
      #pragma unroll
      for (int mt = 0; mt < 2; ++mt) {
        U8 u;
        const int rb = pw + (mt*16 + l15)*LDP + quad*8;
        u.v4[0] = *(const short4v*)&((unsigned short*)PB)[rb];
        u.v4[1] = *(const short4v*)&((unsigned short*)PB)[rb+4];
        pa[mt] = u.v8;
      }
      #pragma unroll
      for (int nt = 0; nt < 4; ++nt) {
        const short8 vb = *(const short8*)&VT[kldsb + (nt*16 + l15)*LDKF + kc*32 + quad*8];
        #pragma unroll
        for (int mt = 0; mt < 2; ++mt) Oc[mt][nt] = MFMA16(pa[mt], vb, Oc[mt][nt]);
      }
    }

    __syncthreads();

    if (t+1 < 32) {
      unsigned short hb[32], lb[32];
      #pragma unroll
      for (int i = 0; i < 8; ++i) {
        float vv[4] = {sr[i].x, sr[i].y, sr[i].z, sr[i].w};
        #pragma unroll
        for (int j = 0; j < 4; ++j) {
          unsigned short h = f2bf(vv[j]);
          hb[i*4+j] = h;
          lb[i*4+j] = f2bf(vv[j] - bf2f(h));
        }
      }
      const int kbase = sh*TILEF + srow*LDKF + sch*32;
      #pragma unroll
      for (int g = 0; g < 4; ++g) {
        U8 wh, wl;
        #pragma unroll
        for (int j = 0; j < 8; ++j) { wh.u[j]=(short)hb[g*8+j]; wl.u[j]=(short)lb[g*8+j]; }
        *(short8*)&KHI[kbase+g*8] = wh.v8;
        *(short8*)&KLO[kbase+g*8] = wl.v8;
      }
      #pragma unroll
      for (int j = 0; j < 32; ++j) VT[sh*TILEF + (sch*32+j)*LDKF + srow] = hb[j];
      __syncthreads();
    }
  }

  float* MO  = (float*)KHI;
  float* MML = (float*)KLO;
  if (hh == 1) {
    #pragma unroll
    for (int mt = 0; mt < 2; ++mt) {
      const int rbase = mg*32 + mt*16 + quad*4;
      #pragma unroll
      for (int nt = 0; nt < 4; ++nt) {
        MO[(rbase+0)*64 + nt*16 + l15] = Oc[mt][nt].x;
        MO[(rbase+1)*64 + nt*16 + l15] = Oc[mt][nt].y;
        MO[(rbase+2)*64 + nt*16 + l15] = Oc[mt][nt].z;
        MO[(rbase+3)*64 + nt*16 + l15] = Oc[mt][nt].w;
      }
      if (l15 == 0) {
        MML[rbase+0] = mo[mt].x; MML[rbase+1] = mo[mt].y;
        MML[rbase+2] = mo[mt].z; MML[rbase+3] = mo[mt].w;
        MML[64+rbase+0] = ls[mt].x; MML[64+rbase+1] = ls[mt].y;
        MML[64+rbase+2] = ls[mt].z; MML[64+rbase+3] = ls[mt].w;
      }
    }
  }
  __syncthreads();
  if (hh == 0) {
    #pragma unroll
    for (int mt = 0; mt < 2; ++mt) {
      const int rbase = mg*32 + mt*16 + quad*4;
      f4 m1, l1;
      m1.x = MML[rbase+0]; m1.y = MML[rbase+1]; m1.z = MML[rbase+2]; m1.w = MML[rbase+3];
      l1.x = MML[64+rbase+0]; l1.y = MML[64+rbase+1]; l1.z = MML[64+rbase+2]; l1.w = MML[64+rbase+3];
      const f4 mn = max4(mo[mt], m1);
      const f4 a0 = exp2v(mo[mt] - mn);
      const f4 a1 = exp2v(m1 - mn);
      f4 lt = ls[mt]*a0 + l1*a1;
      f4 w; w.x = gamma/lt.x; w.y = gamma/lt.y; w.z = gamma/lt.z; w.w = gamma/lt.w;
      #pragma unroll
      for (int nt = 0; nt < 4; ++nt) {
        #pragma unroll
        for (int rg = 0; rg < 4; ++rg) {
          const int rr = rbase + rg;
          const float o1 = MO[rr*64 + nt*16 + l15];
          const float val = (Oc[mt][nt][rg]*a0[rg] + o1*a1[rg]) * w[rg];
          out[((size_t)bb*N_SEQ + qb + rr)*64 + nt*16 + l15] = val;
        }
      }
    }
  }
}

extern "C" void kernel_launch(void* const* d_in, const int* in_sizes, int n_in,
                              void* d_out, int out_size, void* d_ws, size_t ws_size,
                              hipStream_t stream) {
  const float* x  = (const float*)d_in[0];
  const float* wf = (const float*)d_in[1];
  const float* wg = (const float*)d_in[2];
  const float* gm = (const float*)d_in[3];
  float* out = (float*)d_out;

  const size_t XH_OFF = 0;                        // 4*4096*64*2  = 2 MB
  const size_t XT_OFF = 2097152;                  // 2 MB
  const size_t OP_OFF = 4194304;                  // KS*256*4096*4 = 16 MB
  const size_t LP_OFF = OP_OFF + (size_t)KS*256*4096*4;
  const size_t NEED   = LP_OFF + (size_t)KS*256*64*4;

  if (ws_size >= NEED) {
    unsigned short* xhp = (unsigned short*)((char*)d_ws + XH_OFF);
    unsigned short* xtp = (unsigned short*)((char*)d_ws + XT_OFF);
    float* OP = (float*)((char*)d_ws + OP_OFF);
    float* LP = (float*)((char*)d_ws + LP_OFF);
    prep_kernel<<<dim3(256), dim3(256), 0, stream>>>(x, xhp, xtp);
    fattn4_kernel<<<dim3(KS*256), dim3(256), 0, stream>>>(x, wf, wg, xhp, xtp, OP, LP);
    merge_kernel<<<dim3(1024), dim3(256), 0, stream>>>(OP, LP, gm, out);
  } else {
    fattn_fallback<<<dim3(256), dim3(256), 0, stream>>>(x, wf, wg, gm, out);
  }
}

// Round 7
// 96.263 us; speedup vs baseline: 1.0285x; 1.0285x over previous
//
#include <hip/hip_runtime.h>

// FeatureAttention == self-attention: out[b,j,:] = gamma * softmax_i(s * <x_j,x_i>) @ x,
// s = dot(w_f, w_g).  B=4, N=4096, D=64, fp32 in/out.
//
// Round 7: true async double-buffered pipeline, one barrier per iteration.
//  - Block = 128 q x 512 keys (KS=8 splits). 4 waves x 32 q each; all 4 waves share
//    ONE staged 64-key tile per iteration (staging traffic halved vs hh-split).
//  - LDS: KH[2][8KB] + VT[2][8KB] (double buffer) + PB[4][2KB] = 40960 B exactly
//    -> 4 blocks/CU. Loop: barrier -> issue DMA(t+1) into other buffer -> compute(t).
//    The barrier's vmcnt drain now waits on a DMA issued a full compute-phase ago.
//  - No cross-wave merge: each wave owns its q rows; epilogue writes partials direct.
//  - Rest as verified R6: fp16, S^T=K*Q^T, PB psw-swizzle, fixed softmax max.
//  - merge: out = gamma * sum_s O_s / sum_s l_s over 8 splits.
//  - fallback: round-1 bf16 kernel if ws too small.

#define N_SEQ 4096
#define KS    8
#define NT    8            // 64-key tiles per split (512 keys)
#define LOG2E 1.4426950408889634f

typedef __attribute__((ext_vector_type(8))) short short8;
typedef __attribute__((ext_vector_type(4))) short short4v;
typedef __attribute__((ext_vector_type(4))) float f4;
typedef _Float16 half8  __attribute__((ext_vector_type(8)));
typedef _Float16 half4v __attribute__((ext_vector_type(4)));
typedef _Float16 half2t __attribute__((ext_vector_type(2)));
typedef __fp16   fp16x2 __attribute__((ext_vector_type(2)));

union U8  { short8 v8; short4v v4[2]; unsigned short u[8]; };
union HU8 { half8 v; half2t h2[4]; unsigned short u[8]; };
union HU4 { half4v v; half2t h2[2]; unsigned short u[4]; };
union PK  { fp16x2 f; half2t h; };

#define MFMA16(a,b,c) __builtin_amdgcn_mfma_f32_16x16x32_bf16(a,b,c,0,0,0)
#define MFMAH(a,b,c)  __builtin_amdgcn_mfma_f32_16x16x32_f16(a,b,c,0,0,0)

static __device__ __forceinline__ unsigned short f2bf(float f){
  unsigned int u = __float_as_uint(f);
  u += 0x7fffu + ((u>>16)&1u);          // RNE
  return (unsigned short)(u>>16);
}
static __device__ __forceinline__ float bf2f(unsigned short b){
  return __uint_as_float(((unsigned int)b)<<16);
}
static __device__ __forceinline__ half2t pkrtz(float a, float b){
#if __has_builtin(__builtin_amdgcn_cvt_pkrtz)
  PK u; u.f = __builtin_amdgcn_cvt_pkrtz(a, b);
  return u.h;
#else
  half2t r; r.x = (_Float16)a; r.y = (_Float16)b; return r;
#endif
}
static __device__ __forceinline__ float fexp2(float x){
#if __has_builtin(__builtin_amdgcn_exp2f)
  return __builtin_amdgcn_exp2f(x);
#else
  return exp2f(x);
#endif
}
static __device__ __forceinline__ f4 splat4(float v){ f4 r; r.x=v; r.y=v; r.z=v; r.w=v; return r; }
static __device__ __forceinline__ f4 exp2v(f4 v){
  f4 r; r.x=fexp2(v.x); r.y=fexp2(v.y); r.z=fexp2(v.z); r.w=fexp2(v.w); return r;
}
static __device__ __forceinline__ f4 max4(f4 a, f4 b){
  f4 r; r.x=fmaxf(a.x,b.x); r.y=fmaxf(a.y,b.y); r.z=fmaxf(a.z,b.z); r.w=fmaxf(a.w,b.w); return r;
}
static __device__ __forceinline__ f4 shx4(f4 v, int m){
  f4 r; r.x=__shfl_xor(v.x,m,64); r.y=__shfl_xor(v.y,m,64);
        r.z=__shfl_xor(v.z,m,64); r.w=__shfl_xor(v.w,m,64); return r;
}
static __device__ __forceinline__ void gld_lds16(const void* g, void* l){
  __builtin_amdgcn_global_load_lds(
      (const __attribute__((address_space(1))) unsigned int*)g,
      (__attribute__((address_space(3))) unsigned int*)l, 16, 0, 0);
}

// ---------------- prep: x(fp32) -> XH [B][N][64] fp16, XT [B][64][N] fp16 ----------
__global__ __launch_bounds__(256) void prep_kernel(
    const float* __restrict__ x, unsigned short* __restrict__ xh,
    unsigned short* __restrict__ xt)
{
  __shared__ unsigned short T[64][66];
  const int tid = threadIdx.x;
  const int bb  = blockIdx.x >> 6;
  const int n0  = (blockIdx.x & 63) << 6;
  {
    const int r  = tid >> 2;
    const int c4 = tid & 3;
    const float* src = x + ((size_t)(bb*N_SEQ + n0 + r))*64 + c4*16;
    unsigned short h[16];
    #pragma unroll
    for (int i = 0; i < 4; ++i) {
      const float4 f = *(const float4*)(src + i*4);
      HU4 u; u.h2[0] = pkrtz(f.x, f.y); u.h2[1] = pkrtz(f.z, f.w);
      h[i*4+0]=u.u[0]; h[i*4+1]=u.u[1]; h[i*4+2]=u.u[2]; h[i*4+3]=u.u[3];
    }
    unsigned short* dst = xh + ((size_t)(bb*N_SEQ + n0 + r))*64 + c4*16;
    U8 u0, u1;
    #pragma unroll
    for (int j = 0; j < 8; ++j) { u0.u[j]=h[j]; u1.u[j]=h[8+j]; }
    *(short8*)dst = u0.v8; *(short8*)(dst+8) = u1.v8;
    #pragma unroll
    for (int j = 0; j < 16; ++j) T[r][c4*16+j] = h[j];
  }
  __syncthreads();
  {
    const int d = tid >> 2;
    const int g = tid & 3;
    unsigned short o[16];
    #pragma unroll
    for (int j = 0; j < 16; ++j) o[j] = T[g*16+j][d];
    unsigned short* dst = xt + ((size_t)(bb*64 + d))*N_SEQ + n0 + g*16;
    U8 u0, u1;
    #pragma unroll
    for (int j = 0; j < 8; ++j) { u0.u[j]=o[j]; u1.u[j]=o[8+j]; }
    *(short8*)dst = u0.v8; *(short8*)(dst+8) = u1.v8;
  }
}

// ---------------- attention: 128q-block, shared tile, double-buffered ----------------
__global__ __launch_bounds__(256, 4) void fattn5_kernel(
    const float* __restrict__ x, const float* __restrict__ wf,
    const float* __restrict__ wg,
    const unsigned short* __restrict__ xh, const unsigned short* __restrict__ xt,
    float* __restrict__ OP, float* __restrict__ LP)
{
  __shared__ __align__(16) unsigned short KH[2][4096];  // [buf][64k x 64d], ld=64, swizzled
  __shared__ __align__(16) unsigned short VT[2][4096];  // [buf][64d x 64k], ld=64, swizzled
  __shared__ __align__(16) unsigned short PB[4][1024];  // per-wave P chunk [32 q][32 key]

  const int tid  = threadIdx.x;
  const int lane = tid & 63;
  const int wv   = tid >> 6;          // wave owns q rows [qb + wv*32, +32)
  const int quad = lane >> 4;
  const int l15  = lane & 15;
  const int swz  = l15 & 7;
  const int psw  = (l15 & 3) << 1;    // PB 8B-unit XOR swizzle (row-determined)
  const int ks   = blockIdx.x >> 7;   // key split 0..7
  const int rem  = blockIdx.x & 127;
  const int bb   = rem >> 5;          // batch
  const int qb   = (rem & 31) << 7;   // q base (128 rows/block)

  float s = 0.f;
  #pragma unroll
  for (int i = 0; i < 32; ++i) s += wf[i]*wg[i];
  const float s2 = s * LOG2E;

  const float* xb = x + ((size_t)bb * N_SEQ) * 64;

  // Q fragments (B-operand layout: [n=l15][k=quad*8+j]), scaled by s2, fp16
  half8 qf[2][2];
  #pragma unroll
  for (int mt = 0; mt < 2; ++mt) {
    const int row = qb + wv*32 + mt*16 + l15;
    #pragma unroll
    for (int c = 0; c < 2; ++c) {
      const float* src = xb + row*64 + c*32 + quad*8;
      const float4 a0 = *(const float4*)src;
      const float4 a1 = *(const float4*)(src+4);
      HU8 u;
      u.h2[0] = pkrtz(a0.x*s2, a0.y*s2);
      u.h2[1] = pkrtz(a0.z*s2, a0.w*s2);
      u.h2[2] = pkrtz(a1.x*s2, a1.y*s2);
      u.h2[3] = pkrtz(a1.z*s2, a1.w*s2);
      qf[mt][c] = u.v;
    }
  }

  f4 Oc[2][4];
  f4 lsa[2];
  #pragma unroll
  for (int mt = 0; mt < 2; ++mt) {
    lsa[mt] = splat4(0.f);
    #pragma unroll
    for (int nt = 0; nt < 4; ++nt) Oc[mt][nt] = splat4(0.f);
  }

  const int kt0 = ks * 512;
  unsigned short* PBw = PB[wv];

  // staging: one 64-key tile (KH 8KB + VT 8KB) per iteration; 4 DMA per thread.
  // slot p = j*256 + tid (16B units); rr = p>>3 (row), cg = (p&7)^(rr&7) (swizzle).
  int srr[2], scg[2];
  #pragma unroll
  for (int j = 0; j < 2; ++j) {
    const int p = j*256 + tid;
    srr[j] = p >> 3;
    scg[j] = (p & 7) ^ (srr[j] & 7);
  }

  // prologue: stage tile 0 into buffer 0
  #pragma unroll
  for (int j = 0; j < 2; ++j) {
    gld_lds16(xh + ((size_t)(bb*N_SEQ + kt0 + srr[j]))*64 + scg[j]*8,
              &KH[0][(j*256 + wv*64)*8]);
    gld_lds16(xt + ((size_t)(bb*64 + srr[j]))*N_SEQ + kt0 + scg[j]*8,
              &VT[0][(j*256 + wv*64)*8]);
  }

  #pragma unroll 1
  for (int t = 0; t < NT; ++t) {
    __syncthreads();                  // drains DMA(t) -> buf[t&1] ready; buf[(t+1)&1] free
    const int buf = t & 1;

    // issue DMA for t+1 into the other buffer (hidden under compute below)
    if (t + 1 < NT) {
      const int kt = kt0 + (t+1)*64;
      const int nb = buf ^ 1;
      #pragma unroll
      for (int j = 0; j < 2; ++j) {
        gld_lds16(xh + ((size_t)(bb*N_SEQ + kt + srr[j]))*64 + scg[j]*8,
                  &KH[nb][(j*256 + wv*64)*8]);
        gld_lds16(xt + ((size_t)(bb*64 + srr[j]))*N_SEQ + kt + scg[j]*8,
                  &VT[nb][(j*256 + wv*64)*8]);
      }
    }

    // ---- S^T = K * Q^T : C rows = keys (quad*4+reg), cols = q (l15) ----
    f4 St[4][2];
    #pragma unroll
    for (int k2 = 0; k2 < 4; ++k2)
      #pragma unroll
      for (int mt = 0; mt < 2; ++mt) St[k2][mt] = splat4(0.f);

    #pragma unroll
    for (int c = 0; c < 2; ++c) {
      half8 kf[4];
      #pragma unroll
      for (int k2 = 0; k2 < 4; ++k2)
        kf[k2] = *(const half8*)&KH[buf][(k2*16 + l15)*64 + (((c*4 + quad) ^ swz))*8];
      #pragma unroll
      for (int k2 = 0; k2 < 4; ++k2)
        #pragma unroll
        for (int mt = 0; mt < 2; ++mt)
          St[k2][mt] = MFMAH(kf[k2], qf[mt][c], St[k2][mt]);
    }

    // ---- per-kc: p = exp2(S), pack into PB chunk (psw swizzle), PV ----
    #pragma unroll
    for (int kc = 0; kc < 2; ++kc) {
      #pragma unroll
      for (int k2l = 0; k2l < 2; ++k2l) {
        const int k2 = kc*2 + k2l;
        #pragma unroll
        for (int mt = 0; mt < 2; ++mt) {
          const f4 p = exp2v(St[k2][mt]);
          lsa[mt] += p;
          HU4 u; u.h2[0] = pkrtz(p.x, p.y); u.h2[1] = pkrtz(p.z, p.w);
          const int unit = (k2l*4 + quad) ^ psw;
          *(half4v*)&PBw[(mt*16 + l15)*32 + unit*4] = u.v;
        }
      }
      half8 pa[2];
      #pragma unroll
      for (int mt = 0; mt < 2; ++mt) {
        const int u0 = (2*quad) ^ psw;
        pa[mt] = *(const half8*)&PBw[(mt*16 + l15)*32 + u0*4];
      }
      #pragma unroll
      for (int nt = 0; nt < 4; ++nt) {
        const half8 vb = *(const half8*)&VT[buf][(nt*16 + l15)*64 + (((kc*4 + quad) ^ swz))*8];
        #pragma unroll
        for (int mt = 0; mt < 2; ++mt)
          Oc[mt][nt] = MFMAH(pa[mt], vb, Oc[mt][nt]);
      }
    }
  }

  // ---- finalize l (sum over quads; q = wv*32 + mt*16 + l15) ----
  float lsum[2];
  #pragma unroll
  for (int mt = 0; mt < 2; ++mt) {
    float sv = lsa[mt].x + lsa[mt].y + lsa[mt].z + lsa[mt].w;
    sv += __shfl_xor(sv, 16, 64);
    sv += __shfl_xor(sv, 32, 64);
    lsum[mt] = sv;
  }

  // ---- write partials (no cross-wave merge: each wave owns its q rows) ----
  float* op = OP + (size_t)blockIdx.x * 8192;   // [128 q][64 d]
  #pragma unroll
  for (int mt = 0; mt < 2; ++mt) {
    const int rb = wv*32 + mt*16 + quad*4;
    #pragma unroll
    for (int nt = 0; nt < 4; ++nt) {
      op[(rb+0)*64 + nt*16 + l15] = Oc[mt][nt].x;
      op[(rb+1)*64 + nt*16 + l15] = Oc[mt][nt].y;
      op[(rb+2)*64 + nt*16 + l15] = Oc[mt][nt].z;
      op[(rb+3)*64 + nt*16 + l15] = Oc[mt][nt].w;
    }
    if (quad == 0)
      LP[(size_t)blockIdx.x*128 + wv*32 + mt*16 + l15] = lsum[mt];
  }
}

// ---------------- merge: out = gamma * sum_s O_s / sum_s l_s ----------------
__global__ __launch_bounds__(256) void merge_kernel(
    const float* __restrict__ OP, const float* __restrict__ LP,
    const float* __restrict__ gm, float* __restrict__ out)
{
  const int idx = blockIdx.x*256 + threadIdx.x;
  const int e0  = idx*4;
  const int d0  = e0 & 63;
  const int row = e0 >> 6;          // b*4096 + q
  const int bb  = row >> 12;
  const int q   = row & 4095;
  const int qt  = q >> 7;           // 128-row q-tile
  const int qr  = q & 127;
  float4 acc = make_float4(0.f,0.f,0.f,0.f);
  float l = 0.f;
  #pragma unroll
  for (int sct = 0; sct < KS; ++sct) {
    const int blk = sct*128 + bb*32 + qt;
    const float4 o = *(const float4*)(OP + (size_t)blk*8192 + qr*64 + d0);
    acc.x += o.x; acc.y += o.y; acc.z += o.z; acc.w += o.w;
    l += LP[(size_t)blk*128 + qr];
  }
  const float w = gm[0] / l;
  float4 r; r.x = acc.x*w; r.y = acc.y*w; r.z = acc.z*w; r.w = acc.w*w;
  *(float4*)(out + e0) = r;
}

// ---------------- fallback (round-1 kernel, no workspace) ----------------
#define LDKF 72
#define TILEF (64*LDKF)
#define LDP 36

__global__ __launch_bounds__(256) void fattn_fallback(
    const float* __restrict__ x, const float* __restrict__ wf,
    const float* __restrict__ wg, const float* __restrict__ gm,
    float* __restrict__ out)
{
  __shared__ __align__(16) unsigned short KHI[2*TILEF];
  __shared__ __align__(16) unsigned short KLO[2*TILEF];
  __shared__ __align__(16) unsigned short VT [2*TILEF];
  __shared__ __align__(16) unsigned short PB [4*32*LDP];

  const int tid  = threadIdx.x;
  const int lane = tid & 63;
  const int wv   = tid >> 6;
  const int mg   = wv & 1;
  const int hh   = wv >> 1;
  const int quad = lane >> 4;
  const int l15  = lane & 15;
  const int bb   = blockIdx.x >> 6;
  const int qb   = (blockIdx.x & 63) << 6;

  float s = 0.f;
  #pragma unroll
  for (int i = 0; i < 32; ++i) s += wf[i]*wg[i];
  const float s2 = s * LOG2E;
  const float gamma = gm[0];

  const float* xb = x + ((size_t)bb * N_SEQ) * 64;

  short8 qhf[2][2], qlf[2][2];
  #pragma unroll
  for (int mt = 0; mt < 2; ++mt) {
    const int row = qb + mg*32 + mt*16 + l15;
    #pragma unroll
    for (int c = 0; c < 2; ++c) {
      const float* src = xb + row*64 + c*32 + quad*8;
      const float4 a0 = *(const float4*)src;
      const float4 a1 = *(const float4*)(src+4);
      float qv[8] = {a0.x,a0.y,a0.z,a0.w,a1.x,a1.y,a1.z,a1.w};
      U8 vh, vl;
      #pragma unroll
      for (int j = 0; j < 8; ++j) {
        float q = qv[j]*s2;
        unsigned short hb = f2bf(q);
        vh.u[j] = (short)hb;
        vl.u[j] = (short)f2bf(q - bf2f(hb));
      }
      qhf[mt][c] = vh.v8; qlf[mt][c] = vl.v8;
    }
  }

  f4 Oc[2][4], mo[2], ls[2];
  #pragma unroll
  for (int mt = 0; mt < 2; ++mt) {
    mo[mt] = splat4(-1e30f);
    ls[mt] = splat4(0.f);
    #pragma unroll
    for (int nt = 0; nt < 4; ++nt) Oc[mt][nt] = splat4(0.f);
  }

  const int sh   = tid >> 7;
  const int srow = (tid & 127) >> 1;
  const int sch  = tid & 1;

  float4 sr[8];
  {
    const float* sp = xb + (sh*2048 + srow)*64 + sch*32;
    #pragma unroll
    for (int i = 0; i < 8; ++i) sr[i] = *(const float4*)(sp + i*4);
    unsigned short hb[32], lb[32];
    #pragma unroll
    for (int i = 0; i < 8; ++i) {
      float vv[4] = {sr[i].x, sr[i].y, sr[i].z, sr[i].w};
      #pragma unroll
      for (int j = 0; j < 4; ++j) {
        unsigned short h = f2bf(vv[j]);
        hb[i*4+j] = h;
        lb[i*4+j] = f2bf(vv[j] - bf2f(h));
      }
    }
    const int kbase = sh*TILEF + srow*LDKF + sch*32;
    #pragma unroll
    for (int g = 0; g < 4; ++g) {
      U8 wh, wl;
      #pragma unroll
      for (int j = 0; j < 8; ++j) { wh.u[j]=(short)hb[g*8+j]; wl.u[j]=(short)lb[g*8+j]; }
      *(short8*)&KHI[kbase+g*8] = wh.v8;
      *(short8*)&KLO[kbase+g*8] = wl.v8;
    }
    #pragma unroll
    for (int j = 0; j < 32; ++j) VT[sh*TILEF + (sch*32+j)*LDKF + srow] = hb[j];
  }
  __syncthreads();

  #pragma unroll 1
  for (int t = 0; t < 32; ++t) {
    if (t+1 < 32) {
      const float* sp = xb + (sh*2048 + (t+1)*64 + srow)*64 + sch*32;
      #pragma unroll
      for (int i = 0; i < 8; ++i) sr[i] = *(const float4*)(sp + i*4);
    }

    f4 Sa[2][4];
    #pragma unroll
    for (int mt = 0; mt < 2; ++mt)
      #pragma unroll
      for (int n = 0; n < 4; ++n) Sa[mt][n] = splat4(0.f);

    const int kldsb = hh*TILEF;
    #pragma unroll
    for (int n = 0; n < 4; ++n) {
      #pragma unroll
      for (int c = 0; c < 2; ++c) {
        const int off = kldsb + (n*16 + l15)*LDKF + c*32 + quad*8;
        const short8 bh = *(const short8*)&KHI[off];
        const short8 bl = *(const short8*)&KLO[off];
        #pragma unroll
        for (int mt = 0; mt < 2; ++mt) {
          Sa[mt][n] = MFMA16(qhf[mt][c], bh, Sa[mt][n]);
          Sa[mt][n] = MFMA16(qlf[mt][c], bh, Sa[mt][n]);
          Sa[mt][n] = MFMA16(qhf[mt][c], bl, Sa[mt][n]);
        }
      }
    }

    f4 p[2][4];
    #pragma unroll
    for (int mt = 0; mt < 2; ++mt) {
      f4 rm = max4(max4(Sa[mt][0],Sa[mt][1]), max4(Sa[mt][2],Sa[mt][3]));
      rm = max4(rm, shx4(rm,1));
      rm = max4(rm, shx4(rm,2));
      rm = max4(rm, shx4(rm,4));
      rm = max4(rm, shx4(rm,8));
      f4 mn = max4(mo[mt], rm);
      f4 al = exp2v(mo[mt] - mn);
      mo[mt] = mn;
      f4 rs = splat4(0.f);
      #pragma unroll
      for (int n = 0; n < 4; ++n) { p[mt][n] = exp2v(Sa[mt][n] - mn); rs += p[mt][n]; }
      rs += shx4(rs,1); rs += shx4(rs,2); rs += shx4(rs,4); rs += shx4(rs,8);
      ls[mt] = ls[mt]*al + rs;
      #pragma unroll
      for (int nt = 0; nt < 4; ++nt) Oc[mt][nt] *= al;
    }

    const int pw = wv * (32*LDP);
    #pragma unroll
    for (int kc = 0; kc < 2; ++kc) {
      #pragma unroll
      for (int mt = 0; mt < 2; ++mt) {
        #pragma unroll
        for (int n2 = 0; n2 < 2; ++n2) {
          const f4 pv = p[mt][kc*2+n2];
          const int base = pw + (mt*16 + quad*4)*LDP + n2*16 + l15;
          ((unsigned short*)PB)[base        ] = f2bf(pv.x);
          ((unsigned short*)PB)[base +   LDP] = f2bf(pv.y);
          ((unsigned short*)PB)[base + 2*LDP] = f2bf(pv.z);
          ((unsigned short*)PB)[base + 3*LDP] = f2bf(pv.w);
        }
      }
      short8 pa[2];
      #pragma unroll
      for (int mt = 0; mt < 2; ++mt) {
        U8 u;
        const int rb = pw + (mt*16 + l15)*LDP + quad*8;
        u.v4[0] = *(const short4v*)&((unsigned short*)PB)[rb];
        u.v4[1] = *(const short4v*)&((unsigned short*)PB)[rb+4];
        pa[mt] = u.v8;
      }
      #pragma unroll
      for (int nt = 0; nt < 4; ++nt) {
        const short8 vb = *(const short8*)&VT[kldsb + (nt*16 + l15)*LDKF + kc*32 + quad*8];
        #pragma unroll
        for (int mt = 0; mt < 2; ++mt) Oc[mt][nt] = MFMA16(pa[mt], vb, Oc[mt][nt]);
      }
    }

    __syncthreads();

    if (t+1 < 32) {
      unsigned short hb[32], lb[32];
      #pragma unroll
      for (int i = 0; i < 8; ++i) {
        float vv[4] = {sr[i].x, sr[i].y, sr[i].z, sr[i].w};
        #pragma unroll
        for (int j = 0; j < 4; ++j) {
          unsigned short h = f2bf(vv[j]);
          hb[i*4+j] = h;
          lb[i*4+j] = f2bf(vv[j] - bf2f(h));
        }
      }
      const int kbase = sh*TILEF + srow*LDKF + sch*32;
      #pragma unroll
      for (int g = 0; g < 4; ++g) {
        U8 wh, wl;
        #pragma unroll
        for (int j = 0; j < 8; ++j) { wh.u[j]=(short)hb[g*8+j]; wl.u[j]=(short)lb[g*8+j]; }
        *(short8*)&KHI[kbase+g*8] = wh.v8;
        *(short8*)&KLO[kbase+g*8] = wl.v8;
      }
      #pragma unroll
      for (int j = 0; j < 32; ++j) VT[sh*TILEF + (sch*32+j)*LDKF + srow] = hb[j];
      __syncthreads();
    }
  }

  float* MO  = (float*)KHI;
  float* MML = (float*)KLO;
  if (hh == 1) {
    #pragma unroll
    for (int mt = 0; mt < 2; ++mt) {
      const int rbase = mg*32 + mt*16 + quad*4;
      #pragma unroll
      for (int nt = 0; nt < 4; ++nt) {
        MO[(rbase+0)*64 + nt*16 + l15] = Oc[mt][nt].x;
        MO[(rbase+1)*64 + nt*16 + l15] = Oc[mt][nt].y;
        MO[(rbase+2)*64 + nt*16 + l15] = Oc[mt][nt].z;
        MO[(rbase+3)*64 + nt*16 + l15] = Oc[mt][nt].w;
      }
      if (l15 == 0) {
        MML[rbase+0] = mo[mt].x; MML[rbase+1] = mo[mt].y;
        MML[rbase+2] = mo[mt].z; MML[rbase+3] = mo[mt].w;
        MML[64+rbase+0] = ls[mt].x; MML[64+rbase+1] = ls[mt].y;
        MML[64+rbase+2] = ls[mt].z; MML[64+rbase+3] = ls[mt].w;
      }
    }
  }
  __syncthreads();
  if (hh == 0) {
    #pragma unroll
    for (int mt = 0; mt < 2; ++mt) {
      const int rbase = mg*32 + mt*16 + quad*4;
      f4 m1, l1;
      m1.x = MML[rbase+0]; m1.y = MML[rbase+1]; m1.z = MML[rbase+2]; m1.w = MML[rbase+3];
      l1.x = MML[64+rbase+0]; l1.y = MML[64+rbase+1]; l1.z = MML[64+rbase+2]; l1.w = MML[64+rbase+3];
      const f4 mn = max4(mo[mt], m1);
      const f4 a0 = exp2v(mo[mt] - mn);
      const f4 a1 = exp2v(m1 - mn);
      f4 lt = ls[mt]*a0 + l1*a1;
      f4 w; w.x = gamma/lt.x; w.y = gamma/lt.y; w.z = gamma/lt.z; w.w = gamma/lt.w;
      #pragma unroll
      for (int nt = 0; nt < 4; ++nt) {
        #pragma unroll
        for (int rg = 0; rg < 4; ++rg) {
          const int rr = rbase + rg;
          const float o1 = MO[rr*64 + nt*16 + l15];
          const float val = (Oc[mt][nt][rg]*a0[rg] + o1*a1[rg]) * w[rg];
          out[((size_t)bb*N_SEQ + qb + rr)*64 + nt*16 + l15] = val;
        }
      }
    }
  }
}

extern "C" void kernel_launch(void* const* d_in, const int* in_sizes, int n_in,
                              void* d_out, int out_size, void* d_ws, size_t ws_size,
                              hipStream_t stream) {
  const float* x  = (const float*)d_in[0];
  const float* wf = (const float*)d_in[1];
  const float* wg = (const float*)d_in[2];
  const float* gm = (const float*)d_in[3];
  float* out = (float*)d_out;

  const size_t XH_OFF = 0;                         // 4*4096*64*2 = 2 MB
  const size_t XT_OFF = 2097152;                   // 2 MB
  const size_t OP_OFF = 4194304;                   // 1024 blocks * 8192 f32 = 32 MB
  const size_t LP_OFF = OP_OFF + (size_t)1024*8192*4;
  const size_t NEED   = LP_OFF + (size_t)1024*128*4;

  if (ws_size >= NEED) {
    unsigned short* xhp = (unsigned short*)((char*)d_ws + XH_OFF);
    unsigned short* xtp = (unsigned short*)((char*)d_ws + XT_OFF);
    float* OP = (float*)((char*)d_ws + OP_OFF);
    float* LP = (float*)((char*)d_ws + LP_OFF);
    prep_kernel<<<dim3(256), dim3(256), 0, stream>>>(x, xhp, xtp);
    fattn5_kernel<<<dim3(KS*128), dim3(256), 0, stream>>>(x, wf, wg, xhp, xtp, OP, LP);
    merge_kernel<<<dim3(1024), dim3(256), 0, stream>>>(OP, LP, gm, out);
  } else {
    fattn_fallback<<<dim3(256), dim3(256), 0, stream>>>(x, wf, wg, gm, out);
  }
}